// Round 1
// baseline (1457.256 us; speedup 1.0000x reference)
//
#include <hip/hip_runtime.h>

// ---------------------------------------------------------------------------
// VectorQuantizer: z(16,32,32,256) fp32, embedding(256,8192), cluster_size(8192),
// embedding_avg(256,8192).
// Outputs (concat, fp32): quantize_st[4194304], diff[1], embed_ind[16384](as float),
// new_embedding[2097152], new_cluster_size[8192], new_embedding_avg[2097152]
// ---------------------------------------------------------------------------

#define DIMC  256
#define NEMB  8192
#define NROWS 16384

// d_out offsets (float elements)
#define OUT_Q      0u
#define OUT_DIFF   4194304u
#define OUT_IDX    4194305u
#define OUT_NEWEMB 4210689u
#define OUT_NEWCS  6307841u
#define OUT_NEWAVG 6316033u

// d_ws offsets (float elements)
#define WS_EMBSUM 0u          // [NEMB][DIMC] = 2097152 floats (transposed embed_sum)
#define WS_COUNT  2097152u    // [NEMB]
#define WS_DIFF   2105344u    // [1]
#define WS_N      2105345u    // [1]
#define WS_ENORM  2105346u    // [NEMB]
#define WS_IDX    2113538u    // [NROWS] ints
#define WS_PACK_F 2129922u    // u64[NROWS] starts at byte offset WS_PACK_F*4 (8-aligned)

// ---------------------------------------------------------------------------
// ||e||^2 per code. 128 blocks x 256 threads: 64 codes/block, 4 d-groups.
__global__ __launch_bounds__(256) void enorm_kernel(
    const float* __restrict__ emb, float* __restrict__ enorm) {
  __shared__ float red[4][64];
  const int l = threadIdx.x & 63;
  const int dg = threadIdx.x >> 6;
  const int e = blockIdx.x * 64 + l;
  float s = 0.f;
#pragma unroll 8
  for (int d = dg * 64; d < dg * 64 + 64; ++d) {
    const float v = emb[(size_t)d * NEMB + e];
    s = fmaf(v, v, s);
  }
  red[dg][l] = s;
  __syncthreads();
  if (dg == 0) enorm[e] = red[0][l] + red[1][l] + red[2][l] + red[3][l];
}

// ---------------------------------------------------------------------------
// Fused dist GEMM + argmin. Block: 256 threads (16 tx x 16 ty), tile 64 rows x
// 64 codes, 4x4 microtile/thread. Grid: (256 row-tiles, 2 e-halves).
#define TM 64
#define TE 64
#define TK 64
#define EHALF 4096

__global__ __launch_bounds__(256, 2) void argmin_kernel(
    const float* __restrict__ z, const float* __restrict__ emb,
    const float* __restrict__ enorm, unsigned long long* __restrict__ pack) {
  __shared__ float zs[TK][TM + 4];  // transposed: zs[k][row], +4 pad (16B-aligned rows)
  __shared__ float es[TK][TE + 4];  // es[k][e]

  const int r0 = blockIdx.x * TM;
  const int ebase = blockIdx.y * EHALF;
  const int tid = threadIdx.x;
  const int tx = tid & 15;
  const int ty = tid >> 4;

  float minv[4];
  int mini[4];
#pragma unroll
  for (int i = 0; i < 4; ++i) { minv[i] = 3.4028235e38f; mini[i] = 0; }

  for (int et = 0; et < EHALF; et += TE) {
    const int e0 = ebase + et;
    float acc[4][4];
#pragma unroll
    for (int i = 0; i < 4; ++i)
#pragma unroll
      for (int j = 0; j < 4; ++j) acc[i][j] = 0.f;

    for (int k0 = 0; k0 < DIMC; k0 += TK) {
      // stage z tile (64 rows x 64 k, transposed) and emb tile (64 k x 64 e)
#pragma unroll
      for (int it = 0; it < 4; ++it) {
        const int flat = tid + it * 256;   // 0..1023
        const int row = flat >> 4;         // 0..63
        const int slot = flat & 15;        // float4 slot over 64 k (or 64 e)
        const float4 v = *reinterpret_cast<const float4*>(
            &z[(size_t)(r0 + row) * DIMC + k0 + slot * 4]);
        zs[slot * 4 + 0][row] = v.x;
        zs[slot * 4 + 1][row] = v.y;
        zs[slot * 4 + 2][row] = v.z;
        zs[slot * 4 + 3][row] = v.w;
        const float4 w = *reinterpret_cast<const float4*>(
            &emb[(size_t)(k0 + row) * NEMB + e0 + slot * 4]);
        *reinterpret_cast<float4*>(&es[row][slot * 4]) = w;
      }
      __syncthreads();
#pragma unroll 8
      for (int k = 0; k < TK; ++k) {
        const float4 av = *reinterpret_cast<const float4*>(&zs[k][ty * 4]);
        const float4 bv = *reinterpret_cast<const float4*>(&es[k][tx * 4]);
        const float a0 = av.x, a1 = av.y, a2 = av.z, a3 = av.w;
        const float b0 = bv.x, b1 = bv.y, b2 = bv.z, b3 = bv.w;
        acc[0][0] = fmaf(a0, b0, acc[0][0]);
        acc[0][1] = fmaf(a0, b1, acc[0][1]);
        acc[0][2] = fmaf(a0, b2, acc[0][2]);
        acc[0][3] = fmaf(a0, b3, acc[0][3]);
        acc[1][0] = fmaf(a1, b0, acc[1][0]);
        acc[1][1] = fmaf(a1, b1, acc[1][1]);
        acc[1][2] = fmaf(a1, b2, acc[1][2]);
        acc[1][3] = fmaf(a1, b3, acc[1][3]);
        acc[2][0] = fmaf(a2, b0, acc[2][0]);
        acc[2][1] = fmaf(a2, b1, acc[2][1]);
        acc[2][2] = fmaf(a2, b2, acc[2][2]);
        acc[2][3] = fmaf(a2, b3, acc[2][3]);
        acc[3][0] = fmaf(a3, b0, acc[3][0]);
        acc[3][1] = fmaf(a3, b1, acc[3][1]);
        acc[3][2] = fmaf(a3, b2, acc[3][2]);
        acc[3][3] = fmaf(a3, b3, acc[3][3]);
      }
      __syncthreads();
    }
    // epilogue: score = ||e||^2 - 2*dot ; running (min,argmin), first-min tie-break
    const float4 env = *reinterpret_cast<const float4*>(&enorm[e0 + tx * 4]);
    const float en[4] = {env.x, env.y, env.z, env.w};
#pragma unroll
    for (int i = 0; i < 4; ++i)
#pragma unroll
      for (int j = 0; j < 4; ++j) {
        const float s = en[j] - 2.0f * acc[i][j];
        if (s < minv[i]) { minv[i] = s; mini[i] = e0 + tx * 4 + j; }
      }
  }

  // reduce (min,idx) across the 16 tx lanes sharing a row
#pragma unroll
  for (int i = 0; i < 4; ++i) {
    float v = minv[i];
    int ix = mini[i];
#pragma unroll
    for (int off = 1; off < 16; off <<= 1) {
      const float ov = __shfl_xor(v, off, 16);
      const int oi = __shfl_xor(ix, off, 16);
      if (ov < v || (ov == v && oi < ix)) { v = ov; ix = oi; }
    }
    if (tx == 0) {
      const unsigned int fb = __float_as_uint(v);
      const unsigned int s = (fb & 0x80000000u) ? ~fb : (fb | 0x80000000u);
      const unsigned long long key =
          ((unsigned long long)s << 13) | (unsigned long long)ix;
      atomicMin(&pack[r0 + ty * 4 + i], key);
    }
  }
}

// ---------------------------------------------------------------------------
__global__ __launch_bounds__(256) void extract_idx_kernel(
    const unsigned long long* __restrict__ pack, float* __restrict__ out_idx,
    int* __restrict__ ws_idx) {
  const int r = blockIdx.x * 256 + threadIdx.x;
  const int e = (int)(pack[r] & 8191ULL);
  out_idx[r] = (float)e;
  ws_idx[r] = e;
}

// ---------------------------------------------------------------------------
// Gather quantize, diff partial, scatter embed_sum/count. 1 wave per row.
__global__ __launch_bounds__(256) void gather_update_kernel(
    const float* __restrict__ z, const float* __restrict__ emb,
    const int* __restrict__ ws_idx, float* __restrict__ out_q,
    float* __restrict__ embsum, float* __restrict__ count,
    float* __restrict__ diff_acc) {
  const int row = blockIdx.x * 4 + (threadIdx.x >> 6);
  const int lane = threadIdx.x & 63;
  const int e = ws_idx[row];
  const float4 zv =
      *reinterpret_cast<const float4*>(&z[(size_t)row * DIMC + lane * 4]);
  const float q0 = emb[(size_t)(lane * 4 + 0) * NEMB + e];
  const float q1 = emb[(size_t)(lane * 4 + 1) * NEMB + e];
  const float q2 = emb[(size_t)(lane * 4 + 2) * NEMB + e];
  const float q3 = emb[(size_t)(lane * 4 + 3) * NEMB + e];
  const float d0 = q0 - zv.x, d1 = q1 - zv.y, d2 = q2 - zv.z, d3 = q3 - zv.w;
  float4 st;  // quantize_st = z + (q - z), replicating reference op order
  st.x = zv.x + d0; st.y = zv.y + d1; st.z = zv.z + d2; st.w = zv.w + d3;
  *reinterpret_cast<float4*>(&out_q[(size_t)row * DIMC + lane * 4]) = st;

  atomicAdd(&embsum[(size_t)e * DIMC + lane * 4 + 0], zv.x);
  atomicAdd(&embsum[(size_t)e * DIMC + lane * 4 + 1], zv.y);
  atomicAdd(&embsum[(size_t)e * DIMC + lane * 4 + 2], zv.z);
  atomicAdd(&embsum[(size_t)e * DIMC + lane * 4 + 3], zv.w);

  float local = d0 * d0 + d1 * d1 + d2 * d2 + d3 * d3;
#pragma unroll
  for (int off = 32; off > 0; off >>= 1) local += __shfl_down(local, off, 64);

  __shared__ float dred[4];
  if (lane == 0) {
    dred[threadIdx.x >> 6] = local;
    atomicAdd(&count[e], 1.0f);
  }
  __syncthreads();
  if (threadIdx.x == 0)
    atomicAdd(diff_acc, dred[0] + dred[1] + dred[2] + dred[3]);
}

// ---------------------------------------------------------------------------
__global__ __launch_bounds__(256) void finalize_cluster_kernel(
    const float* __restrict__ cs, const float* __restrict__ count,
    float* __restrict__ out_ncs, float* __restrict__ out_diff,
    const float* __restrict__ diff_acc, float* __restrict__ n_acc) {
  const int g = blockIdx.x * 256 + threadIdx.x;
  const float ncs = cs[g] * 0.99f + 0.01f * count[g];
  out_ncs[g] = ncs;
  float s = ncs;
#pragma unroll
  for (int off = 32; off > 0; off >>= 1) s += __shfl_down(s, off, 64);
  __shared__ float red[4];
  const int w = threadIdx.x >> 6;
  if ((threadIdx.x & 63) == 0) red[w] = s;
  __syncthreads();
  if (threadIdx.x == 0) atomicAdd(n_acc, red[0] + red[1] + red[2] + red[3]);
  if (g == 0) out_diff[0] = diff_acc[0] * (1.0f / 4194304.0f);
}

// ---------------------------------------------------------------------------
__global__ __launch_bounds__(256) void finalize_embed_kernel(
    const float* __restrict__ eavg, const float* __restrict__ embsum,
    const float* __restrict__ ncs_out, const float* __restrict__ n_acc,
    float* __restrict__ out_avg, float* __restrict__ out_emb) {
  const int g = blockIdx.x * 256 + threadIdx.x;  // d*NEMB + e
  const int d = g >> 13;
  const int e = g & 8191;
  const float avg = eavg[g] * 0.99f + 0.01f * embsum[(size_t)e * DIMC + d];
  out_avg[g] = avg;
  const float n = n_acc[0];
  const float ncs = ncs_out[e];
  const float smoothed = (ncs + 1e-5f) / (n + (float)NEMB * 1e-5f) * n;
  out_emb[g] = avg / smoothed;
}

// ---------------------------------------------------------------------------
extern "C" void kernel_launch(void* const* d_in, const int* in_sizes, int n_in,
                              void* d_out, int out_size, void* d_ws,
                              size_t ws_size, hipStream_t stream) {
  const float* z = (const float*)d_in[0];
  const float* emb = (const float*)d_in[1];
  const float* cs = (const float*)d_in[2];
  const float* eavg = (const float*)d_in[3];
  float* out = (float*)d_out;
  float* ws = (float*)d_ws;

  float* ws_embsum = ws + WS_EMBSUM;
  float* ws_count = ws + WS_COUNT;
  float* ws_diff = ws + WS_DIFF;
  float* ws_n = ws + WS_N;
  float* ws_enorm = ws + WS_ENORM;
  int* ws_idx = (int*)(ws + WS_IDX);
  unsigned long long* ws_pack = (unsigned long long*)(ws + WS_PACK_F);

  // zero embsum+count+diff+n (contiguous), 0xFF-init pack (u64 max)
  hipMemsetAsync(ws, 0, (size_t)(WS_N + 1) * sizeof(float), stream);
  hipMemsetAsync(ws_pack, 0xFF, (size_t)NROWS * sizeof(unsigned long long),
                 stream);

  enorm_kernel<<<NEMB / 64, 256, 0, stream>>>(emb, ws_enorm);
  argmin_kernel<<<dim3(NROWS / TM, NEMB / EHALF), 256, 0, stream>>>(
      z, emb, ws_enorm, ws_pack);
  extract_idx_kernel<<<NROWS / 256, 256, 0, stream>>>(ws_pack, out + OUT_IDX,
                                                      ws_idx);
  gather_update_kernel<<<NROWS / 4, 256, 0, stream>>>(
      z, emb, ws_idx, out + OUT_Q, ws_embsum, ws_count, ws_diff);
  finalize_cluster_kernel<<<NEMB / 256, 256, 0, stream>>>(
      cs, ws_count, out + OUT_NEWCS, out + OUT_DIFF, ws_diff, ws_n);
  finalize_embed_kernel<<<(DIMC * NEMB) / 256, 256, 0, stream>>>(
      eavg, ws_embsum, out + OUT_NEWCS, ws_n, out + OUT_NEWAVG,
      out + OUT_NEWEMB);
}

// Round 2
// 414.841 us; speedup vs baseline: 3.5128x; 3.5128x over previous
//
#include <hip/hip_runtime.h>

// ---------------------------------------------------------------------------
// VectorQuantizer: z(16,32,32,256) fp32, embedding(256,8192), cluster_size(8192),
// embedding_avg(256,8192).
// Outputs (concat, fp32): quantize_st[4194304], diff[1], embed_ind[16384](as float),
// new_embedding[2097152], new_cluster_size[8192], new_embedding_avg[2097152]
//
// R2 strategy: distance GEMM on MFMA pipe via 3-term bf16 split
//   z.e = zh.eh + zh.el + zl.eh   (drop zl.el, rel err ~2^-18)
// Scratch aliasing (keeps ws at the proven 8.65 MB):
//   z hi/lo bf16 planes  -> OUT_Q region      (overwritten later by gather)
//   emb fp32 transposed  -> OUT_NEWEMB region (overwritten later by finalize1/2)
//   embed_sum [e][d]     -> OUT_NEWAVG region (overwritten later by finalize2)
//   emb hi/lo bf16 transposed planes -> ws
// ---------------------------------------------------------------------------

#define DIMC  256
#define NEMB  8192
#define NROWS 16384

// d_out offsets (float elements)
#define OUT_Q      0u
#define OUT_DIFF   4194304u
#define OUT_IDX    4194305u
#define OUT_NEWEMB 4210689u
#define OUT_NEWCS  6307841u
#define OUT_NEWAVG 6316033u

// d_ws offsets (float elements)
#define WS_EHI    0u          // bf16[8192][256] transposed emb hi = 1048576 floats
#define WS_ELO    1048576u    // bf16[8192][256] transposed emb lo
#define WS_COUNT  2097152u    // [NEMB]
#define WS_DIFF   2105344u    // [1]
#define WS_N      2105345u    // [1]
#define WS_ENORM  2105346u    // [NEMB]
#define WS_IDX    2113538u    // [NROWS] ints
#define WS_PACK_F 2129922u    // u64[NROWS] at byte offset *4 (8-aligned)

typedef __attribute__((ext_vector_type(8))) short short8;
typedef __attribute__((ext_vector_type(4))) float f32x4;

// round-to-nearest-even fp32 -> bf16 split: x ~= hi + lo
__device__ inline void split_bf16(float x, unsigned short& h, unsigned short& l) {
  unsigned u = __float_as_uint(x);
  unsigned r = u + 0x7FFFu + ((u >> 16) & 1u);
  h = (unsigned short)(r >> 16);
  float hf = __uint_as_float((unsigned)h << 16);
  float lo = x - hf;
  unsigned u2 = __float_as_uint(lo);
  unsigned r2 = u2 + 0x7FFFu + ((u2 >> 16) & 1u);
  l = (unsigned short)(r2 >> 16);
}

// ---------------------------------------------------------------------------
// z[16384][256] fp32 -> z_hi/z_lo bf16 planes (same layout). 4 el/thread.
__global__ __launch_bounds__(256) void prep_z_kernel(
    const float* __restrict__ z, unsigned short* __restrict__ z_hi,
    unsigned short* __restrict__ z_lo) {
  const int idx = blockIdx.x * 256 + threadIdx.x;  // float4 index
  const float4 v = reinterpret_cast<const float4*>(z)[idx];
  ushort4 h, l;
  split_bf16(v.x, h.x, l.x);
  split_bf16(v.y, h.y, l.y);
  split_bf16(v.z, h.z, l.z);
  split_bf16(v.w, h.w, l.w);
  reinterpret_cast<ushort4*>(z_hi)[idx] = h;
  reinterpret_cast<ushort4*>(z_lo)[idx] = l;
}

// ---------------------------------------------------------------------------
// emb[k][n] fp32 -> transposed planes: e_hi/e_lo bf16 [n][k], embt fp32 [n][k].
// 64x64 tiles via LDS. grid (128 n-tiles, 4 k-tiles).
__global__ __launch_bounds__(256) void prep_emb_kernel(
    const float* __restrict__ emb, unsigned short* __restrict__ e_hi,
    unsigned short* __restrict__ e_lo, float* __restrict__ embt) {
  __shared__ float tile[64][68];
  const int t = threadIdx.x;
  const int n0 = blockIdx.x * 64;
  const int k0 = blockIdx.y * 64;
  const int c4 = (t & 15) * 4;
  const int rr = t >> 4;
#pragma unroll
  for (int i = 0; i < 4; ++i) {
    const int kl = rr + i * 16;
    const float4 v = *reinterpret_cast<const float4*>(
        &emb[(size_t)(k0 + kl) * NEMB + n0 + c4]);
    *reinterpret_cast<float4*>(&tile[kl][c4]) = v;
  }
  __syncthreads();
#pragma unroll
  for (int i = 0; i < 4; ++i) {
    const int nr = rr + i * 16;
    float4 v;
    v.x = tile[c4 + 0][nr];
    v.y = tile[c4 + 1][nr];
    v.z = tile[c4 + 2][nr];
    v.w = tile[c4 + 3][nr];
    const size_t off = (size_t)(n0 + nr) * DIMC + k0 + c4;
    *reinterpret_cast<float4*>(&embt[off]) = v;
    ushort4 h, l;
    split_bf16(v.x, h.x, l.x);
    split_bf16(v.y, h.y, l.y);
    split_bf16(v.z, h.z, l.z);
    split_bf16(v.w, h.w, l.w);
    *reinterpret_cast<ushort4*>(&e_hi[off]) = h;
    *reinterpret_cast<ushort4*>(&e_lo[off]) = l;
  }
}

// ---------------------------------------------------------------------------
// ||e||^2 per code (exact fp32 from original emb).
__global__ __launch_bounds__(256) void enorm_kernel(
    const float* __restrict__ emb, float* __restrict__ enorm) {
  __shared__ float red[4][64];
  const int l = threadIdx.x & 63;
  const int dg = threadIdx.x >> 6;
  const int e = blockIdx.x * 64 + l;
  float s = 0.f;
#pragma unroll 8
  for (int d = dg * 64; d < dg * 64 + 64; ++d) {
    const float v = emb[(size_t)d * NEMB + e];
    s = fmaf(v, v, s);
  }
  red[dg][l] = s;
  __syncthreads();
  if (dg == 0) enorm[e] = red[0][l] + red[1][l] + red[2][l] + red[3][l];
}

// ---------------------------------------------------------------------------
// MFMA dist+argmin. Block 256 thr = 4 waves, tile 128 rows x 128 codes,
// wave tile 64x64 (4x4 of 16x16x32 mfma), BK=64, 3 mfma per (frag,kstep).
// Grid 512: bid>>2 = row-tile, bid&3 = 2048-code chunk (XCD L2 residency).
// LDS tiles: [outer 128][16 chunks of 16B]; chunk p of row n holds k-octet
// ((p&7)^(n&7)) of plane (p>>3)  -> ds_read_b128 frag reads are 2-way (free).
__global__ __launch_bounds__(256, 2) void argmin_mfma_kernel(
    const unsigned short* __restrict__ z_hi, const unsigned short* __restrict__ z_lo,
    const unsigned short* __restrict__ e_hi, const unsigned short* __restrict__ e_lo,
    const float* __restrict__ enorm, unsigned long long* __restrict__ pack) {
  __shared__ short za[16384];  // 32 KB
  __shared__ short eb[16384];  // 32 KB
  const int tid = threadIdx.x;
  const int bid = blockIdx.x;
  const int r0 = (bid >> 2) * 128;
  const int ebase = (bid & 3) * 2048;
  const int tx = tid & 15;
  const int q = (tid >> 4) & 3;
  const int wave = tid >> 6;
  const int wm = wave & 1;   // row half
  const int wn = wave >> 1;  // col half

  float rmin[4][4];
  int ridx[4][4];
#pragma unroll
  for (int i = 0; i < 4; ++i)
#pragma unroll
    for (int r = 0; r < 4; ++r) { rmin[i][r] = 3.4028235e38f; ridx[i][r] = 0; }

  for (int nt = 0; nt < 16; ++nt) {
    const int n0 = ebase + nt * 128;
    f32x4 acc[4][4];
#pragma unroll
    for (int i = 0; i < 4; ++i)
#pragma unroll
      for (int j = 0; j < 4; ++j) acc[i][j] = (f32x4)0.0f;

    for (int kt = 0; kt < 4; ++kt) {
      const int k0 = kt * 64;
      __syncthreads();  // previous tile fully consumed
#pragma unroll
      for (int it = 0; it < 8; ++it) {
        const int P = tid + it * 256;  // chunk id 0..2047
        const int row = P >> 4;
        const int p = P & 15;
        const int o = (p & 7) ^ (row & 7);
        const unsigned short* zsrc =
            ((p & 8) ? z_lo : z_hi) + (size_t)(r0 + row) * DIMC + k0 + o * 8;
        __builtin_amdgcn_global_load_lds(
            (const __attribute__((address_space(1))) unsigned int*)zsrc,
            (__attribute__((address_space(3))) unsigned int*)&za[P * 8], 16, 0, 0);
        const unsigned short* esrc =
            ((p & 8) ? e_lo : e_hi) + (size_t)(n0 + row) * DIMC + k0 + o * 8;
        __builtin_amdgcn_global_load_lds(
            (const __attribute__((address_space(1))) unsigned int*)esrc,
            (__attribute__((address_space(3))) unsigned int*)&eb[P * 8], 16, 0, 0);
      }
      __syncthreads();  // drain + publish
#pragma unroll
      for (int ks = 0; ks < 2; ++ks) {
        short8 ah[4], al[4], bh[4], bl[4];
#pragma unroll
        for (int i = 0; i < 4; ++i) {
          const int rl = wm * 64 + i * 16 + tx;
          const int oa = (ks * 4 + q) ^ (rl & 7);
          ah[i] = *reinterpret_cast<const short8*>(&za[rl * 128 + oa * 8]);
          al[i] = *reinterpret_cast<const short8*>(&za[rl * 128 + (oa + 8) * 8]);
          const int cl = wn * 64 + i * 16 + tx;
          const int ob = (ks * 4 + q) ^ (cl & 7);
          bh[i] = *reinterpret_cast<const short8*>(&eb[cl * 128 + ob * 8]);
          bl[i] = *reinterpret_cast<const short8*>(&eb[cl * 128 + (ob + 8) * 8]);
        }
#pragma unroll
        for (int i = 0; i < 4; ++i)
#pragma unroll
          for (int j = 0; j < 4; ++j) {
            acc[i][j] = __builtin_amdgcn_mfma_f32_16x16x32_bf16(ah[i], bh[j],
                                                               acc[i][j], 0, 0, 0);
            acc[i][j] = __builtin_amdgcn_mfma_f32_16x16x32_bf16(ah[i], bl[j],
                                                               acc[i][j], 0, 0, 0);
            acc[i][j] = __builtin_amdgcn_mfma_f32_16x16x32_bf16(al[i], bh[j],
                                                               acc[i][j], 0, 0, 0);
          }
      }
    }
    // epilogue: score = ||e||^2 - 2*dot, running first-min argmin.
    // D frag: row = q*4 + r, col = tx (per m89-verified 16x16 C/D layout)
#pragma unroll
    for (int j = 0; j < 4; ++j) {
      const int col = n0 + wn * 64 + j * 16 + tx;
      const float en = enorm[col];
#pragma unroll
      for (int i = 0; i < 4; ++i)
#pragma unroll
        for (int r = 0; r < 4; ++r) {
          const float s = en - 2.0f * acc[i][j][r];
          if (s < rmin[i][r]) { rmin[i][r] = s; ridx[i][r] = col; }
        }
    }
  }
  // reduce across the 16 tx lanes (same rows), then one atomicMin per row
#pragma unroll
  for (int i = 0; i < 4; ++i)
#pragma unroll
    for (int r = 0; r < 4; ++r) {
      float v = rmin[i][r];
      int ix = ridx[i][r];
#pragma unroll
      for (int off = 1; off < 16; off <<= 1) {
        const float ov = __shfl_xor(v, off, 64);
        const int oi = __shfl_xor(ix, off, 64);
        if (ov < v || (ov == v && oi < ix)) { v = ov; ix = oi; }
      }
      if (tx == 0) {
        const unsigned int fb = __float_as_uint(v);
        const unsigned int sb = (fb & 0x80000000u) ? ~fb : (fb | 0x80000000u);
        const unsigned long long key =
            ((unsigned long long)sb << 13) | (unsigned long long)(unsigned)ix;
        atomicMin(&pack[r0 + wm * 64 + i * 16 + q * 4 + r], key);
      }
    }
}

// ---------------------------------------------------------------------------
__global__ __launch_bounds__(256) void extract_idx_kernel(
    const unsigned long long* __restrict__ pack, float* __restrict__ out_idx,
    int* __restrict__ ws_idx) {
  const int r = blockIdx.x * 256 + threadIdx.x;
  const int e = (int)(pack[r] & 8191ULL);
  out_idx[r] = (float)e;
  ws_idx[r] = e;
}

// ---------------------------------------------------------------------------
// Gather quantize (from fp32 transposed emb -> coalesced rows), diff partial,
// scatter embed_sum/count. 1 wave per row.
__global__ __launch_bounds__(256) void gather_update_kernel(
    const float* __restrict__ z, const float* __restrict__ embt,
    const int* __restrict__ ws_idx, float* __restrict__ out_q,
    float* __restrict__ embsum, float* __restrict__ count,
    float* __restrict__ diff_acc) {
  const int row = blockIdx.x * 4 + (threadIdx.x >> 6);
  const int lane = threadIdx.x & 63;
  const int e = ws_idx[row];
  const float4 zv =
      *reinterpret_cast<const float4*>(&z[(size_t)row * DIMC + lane * 4]);
  const float4 qv =
      *reinterpret_cast<const float4*>(&embt[(size_t)e * DIMC + lane * 4]);
  const float d0 = qv.x - zv.x, d1 = qv.y - zv.y, d2 = qv.z - zv.z,
              d3 = qv.w - zv.w;
  float4 st;  // z + (q - z), replicating reference op order
  st.x = zv.x + d0; st.y = zv.y + d1; st.z = zv.z + d2; st.w = zv.w + d3;
  *reinterpret_cast<float4*>(&out_q[(size_t)row * DIMC + lane * 4]) = st;

  atomicAdd(&embsum[(size_t)e * DIMC + lane * 4 + 0], zv.x);
  atomicAdd(&embsum[(size_t)e * DIMC + lane * 4 + 1], zv.y);
  atomicAdd(&embsum[(size_t)e * DIMC + lane * 4 + 2], zv.z);
  atomicAdd(&embsum[(size_t)e * DIMC + lane * 4 + 3], zv.w);

  float local = d0 * d0 + d1 * d1 + d2 * d2 + d3 * d3;
#pragma unroll
  for (int off = 32; off > 0; off >>= 1) local += __shfl_down(local, off, 64);

  __shared__ float dred[4];
  if (lane == 0) {
    dred[threadIdx.x >> 6] = local;
    atomicAdd(&count[e], 1.0f);
  }
  __syncthreads();
  if (threadIdx.x == 0)
    atomicAdd(diff_acc, dred[0] + dred[1] + dred[2] + dred[3]);
}

// ---------------------------------------------------------------------------
__global__ __launch_bounds__(256) void finalize_cluster_kernel(
    const float* __restrict__ cs, const float* __restrict__ count,
    float* __restrict__ out_ncs, float* __restrict__ out_diff,
    const float* __restrict__ diff_acc, float* __restrict__ n_acc) {
  const int g = blockIdx.x * 256 + threadIdx.x;
  const float ncs = cs[g] * 0.99f + 0.01f * count[g];
  out_ncs[g] = ncs;
  float s = ncs;
#pragma unroll
  for (int off = 32; off > 0; off >>= 1) s += __shfl_down(s, off, 64);
  __shared__ float red[4];
  const int w = threadIdx.x >> 6;
  if ((threadIdx.x & 63) == 0) red[w] = s;
  __syncthreads();
  if (threadIdx.x == 0) atomicAdd(n_acc, red[0] + red[1] + red[2] + red[3]);
  if (g == 0) out_diff[0] = diff_acc[0] * (1.0f / 4194304.0f);
}

// ---------------------------------------------------------------------------
// finalize1: avgtmp[d][e] = 0.99*eavg + 0.01*embsum[e][d]  (tiled transpose).
// avgtmp lives at OUT_NEWEMB (overwrites embt scratch, which is done).
__global__ __launch_bounds__(256) void finalize1_kernel(
    const float* __restrict__ eavg, const float* __restrict__ embsum,
    float* __restrict__ avgtmp) {
  __shared__ float tile[64][68];
  const int t = threadIdx.x;
  const int e0 = blockIdx.x * 64;
  const int d0 = blockIdx.y * 64;
  const int c4 = (t & 15) * 4;
  const int rr = t >> 4;
#pragma unroll
  for (int i = 0; i < 4; ++i) {
    const int er = rr + i * 16;
    const float4 v = *reinterpret_cast<const float4*>(
        &embsum[(size_t)(e0 + er) * DIMC + d0 + c4]);
    *reinterpret_cast<float4*>(&tile[er][c4]) = v;
  }
  __syncthreads();
#pragma unroll
  for (int i = 0; i < 4; ++i) {
    const int dr = rr + i * 16;
    const size_t g = (size_t)(d0 + dr) * NEMB + e0 + c4;
    const float4 av = *reinterpret_cast<const float4*>(&eavg[g]);
    float4 o;
    o.x = av.x * 0.99f + 0.01f * tile[c4 + 0][dr];
    o.y = av.y * 0.99f + 0.01f * tile[c4 + 1][dr];
    o.z = av.z * 0.99f + 0.01f * tile[c4 + 2][dr];
    o.w = av.w * 0.99f + 0.01f * tile[c4 + 3][dr];
    *reinterpret_cast<float4*>(&avgtmp[g]) = o;
  }
}

// ---------------------------------------------------------------------------
// finalize2: out_avg[g] = avgtmp[g]; out_emb[g] = avgtmp[g]/smoothed(e).
// out_emb region IS avgtmp (in-place: read own g, then overwrite) and
// out_avg region overwrites the embsum scratch (done).
__global__ __launch_bounds__(256) void finalize2_kernel(
    const float* __restrict__ ncs_out, const float* __restrict__ n_acc,
    float* __restrict__ out_avg, float* __restrict__ out_emb_and_avgtmp) {
  const int g = blockIdx.x * 256 + threadIdx.x;
  const int e = g & 8191;
  const float avg = out_emb_and_avgtmp[g];
  const float n = n_acc[0];
  const float ncs = ncs_out[e];
  const float smoothed = (ncs + 1e-5f) / (n + (float)NEMB * 1e-5f) * n;
  out_avg[g] = avg;
  out_emb_and_avgtmp[g] = avg / smoothed;
}

// ---------------------------------------------------------------------------
extern "C" void kernel_launch(void* const* d_in, const int* in_sizes, int n_in,
                              void* d_out, int out_size, void* d_ws,
                              size_t ws_size, hipStream_t stream) {
  const float* z = (const float*)d_in[0];
  const float* emb = (const float*)d_in[1];
  const float* cs = (const float*)d_in[2];
  const float* eavg = (const float*)d_in[3];
  float* out = (float*)d_out;
  float* ws = (float*)d_ws;

  unsigned short* e_hi = (unsigned short*)(ws + WS_EHI);
  unsigned short* e_lo = (unsigned short*)(ws + WS_ELO);
  float* ws_count = ws + WS_COUNT;
  float* ws_diff = ws + WS_DIFF;
  float* ws_n = ws + WS_N;
  float* ws_enorm = ws + WS_ENORM;
  int* ws_idx = (int*)(ws + WS_IDX);
  unsigned long long* ws_pack = (unsigned long long*)(ws + WS_PACK_F);

  // scratch aliased into d_out (re-poisoned before every call; all regions
  // are fully rewritten by the final kernels below):
  unsigned short* z_hi = (unsigned short*)(out + OUT_Q);           // 8.39 MB
  unsigned short* z_lo = (unsigned short*)(out + OUT_Q + 2097152); // 8.39 MB
  float* embt = out + OUT_NEWEMB;    // fp32 [e][d], later avgtmp/new_embedding
  float* embsum = out + OUT_NEWAVG;  // [e][d] scatter target, later new_avg

  hipMemsetAsync(ws_count, 0, (size_t)(NEMB + 2) * sizeof(float), stream);
  hipMemsetAsync(ws_pack, 0xFF, (size_t)NROWS * sizeof(unsigned long long),
                 stream);
  hipMemsetAsync(embsum, 0, (size_t)NEMB * DIMC * sizeof(float), stream);

  prep_z_kernel<<<4096, 256, 0, stream>>>(z, z_hi, z_lo);
  prep_emb_kernel<<<dim3(NEMB / 64, DIMC / 64), 256, 0, stream>>>(emb, e_hi,
                                                                  e_lo, embt);
  enorm_kernel<<<NEMB / 64, 256, 0, stream>>>(emb, ws_enorm);
  argmin_mfma_kernel<<<512, 256, 0, stream>>>(z_hi, z_lo, e_hi, e_lo, ws_enorm,
                                              ws_pack);
  extract_idx_kernel<<<NROWS / 256, 256, 0, stream>>>(ws_pack, out + OUT_IDX,
                                                      ws_idx);
  gather_update_kernel<<<NROWS / 4, 256, 0, stream>>>(
      z, embt, ws_idx, out + OUT_Q, embsum, ws_count, ws_diff);
  finalize_cluster_kernel<<<NEMB / 256, 256, 0, stream>>>(
      cs, ws_count, out + OUT_NEWCS, out + OUT_DIFF, ws_diff, ws_n);
  finalize1_kernel<<<dim3(NEMB / 64, DIMC / 64), 256, 0, stream>>>(
      eavg, embsum, embt /* avgtmp */);
  finalize2_kernel<<<(DIMC * NEMB) / 256, 256, 0, stream>>>(
      out + OUT_NEWCS, ws_n, out + OUT_NEWAVG /* final new_avg */,
      embt /* avgtmp -> new_embedding in place */);
}

// Round 4
// 395.958 us; speedup vs baseline: 3.6803x; 1.0477x over previous
//
#include <hip/hip_runtime.h>

// ---------------------------------------------------------------------------
// VectorQuantizer: z(16,32,32,256) fp32, embedding(256,8192), cluster_size(8192),
// embedding_avg(256,8192).
// Outputs (concat, fp32): quantize_st[4194304], diff[1], embed_ind[16384](as float),
// new_embedding[2097152], new_cluster_size[8192], new_embedding_avg[2097152]
//
// R4: R2-proven argmin path (16x16x32 mfma, exact enorm, pack in ws @16-aligned,
//     memset 0xFF init) + R3's validated tail fusion (fused prep, gather w/ idx,
//     fin_a/fin2). The R3-only deltas (32x32 mapping, enorm4 partials, pack in
//     d_out w/ kernel uint4 init) are reverted pending bisection.
// Aliasing timeline:
//   OUT_Q:      z_hi/z_lo planes (prep) -> quantize_st (gather)
//   OUT_NEWEMB: avgtmp (fin_a) -> new_embedding in place (fin2)
//   OUT_NEWAVG: embsum [e][d] zeroed (prep), scattered (gather), read (fin_a),
//               -> new_embedding_avg (fin2)
// ---------------------------------------------------------------------------

#define DIMC  256
#define NEMB  8192
#define NROWS 16384

// d_out offsets (float elements)
#define OUT_Q      0u
#define OUT_DIFF   4194304u
#define OUT_IDX    4194305u
#define OUT_NEWEMB 4210689u
#define OUT_NEWCS  6307841u
#define OUT_NEWAVG 6316033u

// d_ws offsets (float elements) — total 2146308 floats = 8.59 MB (< proven 8.65)
#define WS_EHI    0u          // bf16[8192][256] transposed emb hi
#define WS_ELO    1048576u    // bf16[8192][256] transposed emb lo
#define WS_COUNT  2097152u    // [NEMB]
#define WS_DIFF   2105344u    // [1]
#define WS_N      2105345u    // [1]
#define WS_ENORM  2105346u    // [NEMB] exact ||e||^2
#define WS_PACK   2113540u    // u64[NROWS]; byte 8454160 % 16 == 0 (16-aligned)

typedef __attribute__((ext_vector_type(8))) short short8;
typedef __attribute__((ext_vector_type(4))) float f32x4;

// round-to-nearest-even fp32 -> bf16 split: x ~= hi + lo
__device__ inline void split_bf16(float x, unsigned short& h, unsigned short& l) {
  unsigned u = __float_as_uint(x);
  unsigned r = u + 0x7FFFu + ((u >> 16) & 1u);
  h = (unsigned short)(r >> 16);
  float hf = __uint_as_float((unsigned)h << 16);
  float lo = x - hf;
  unsigned u2 = __float_as_uint(lo);
  unsigned r2 = u2 + 0x7FFFu + ((u2 >> 16) & 1u);
  l = (unsigned short)(r2 >> 16);
}

__device__ inline float bf16_f(unsigned short u) {
  return __uint_as_float((unsigned)u << 16);
}

// ---------------------------------------------------------------------------
// Fused prep: [0,1024) z split | [1024,1536) emb transpose/split |
// [1536,2048) embsum zero | [2048,2176) exact enorm (R2 algorithm verbatim)
__global__ __launch_bounds__(256) void prep_kernel(
    const float* __restrict__ z, const float* __restrict__ emb,
    unsigned short* __restrict__ z_hi, unsigned short* __restrict__ z_lo,
    unsigned short* __restrict__ e_hi, unsigned short* __restrict__ e_lo,
    float* __restrict__ enorm, float* __restrict__ embsum) {
  const int b = blockIdx.x;
  const int t = threadIdx.x;
  __shared__ float tile[64][68];
  __shared__ float red[4][64];

  if (b < 1024) {
#pragma unroll
    for (int it = 0; it < 4; ++it) {
      const int idx = (b * 256 + t) + it * 262144;
      const float4 v = reinterpret_cast<const float4*>(z)[idx];
      ushort4 h, l;
      split_bf16(v.x, h.x, l.x);
      split_bf16(v.y, h.y, l.y);
      split_bf16(v.z, h.z, l.z);
      split_bf16(v.w, h.w, l.w);
      reinterpret_cast<ushort4*>(z_hi)[idx] = h;
      reinterpret_cast<ushort4*>(z_lo)[idx] = l;
    }
  } else if (b < 1536) {
    const int bb = b - 1024;
    const int n0 = (bb & 127) * 64;
    const int k0 = (bb >> 7) * 64;
    const int c4 = (t & 15) * 4;
    const int rr = t >> 4;
#pragma unroll
    for (int i = 0; i < 4; ++i) {
      const int kl = rr + i * 16;
      const float4 v = *reinterpret_cast<const float4*>(
          &emb[(size_t)(k0 + kl) * NEMB + n0 + c4]);
      *reinterpret_cast<float4*>(&tile[kl][c4]) = v;
    }
    __syncthreads();
#pragma unroll
    for (int i = 0; i < 4; ++i) {
      const int nr = rr + i * 16;
      float4 v;
      v.x = tile[c4 + 0][nr];
      v.y = tile[c4 + 1][nr];
      v.z = tile[c4 + 2][nr];
      v.w = tile[c4 + 3][nr];
      const size_t off = (size_t)(n0 + nr) * DIMC + k0 + c4;
      ushort4 h, l;
      split_bf16(v.x, h.x, l.x);
      split_bf16(v.y, h.y, l.y);
      split_bf16(v.z, h.z, l.z);
      split_bf16(v.w, h.w, l.w);
      *reinterpret_cast<ushort4*>(&e_hi[off]) = h;
      *reinterpret_cast<ushort4*>(&e_lo[off]) = l;
    }
  } else if (b < 2048) {
    const int bb = b - 1536;
    const float4 zero = {0.f, 0.f, 0.f, 0.f};
#pragma unroll
    for (int it = 0; it < 4; ++it)
      reinterpret_cast<float4*>(embsum)[bb * 1024 + t + it * 256] = zero;
  } else {
    // exact enorm, R2 summation order: fmaf chain over 64 d, then 4-way add
    const int l = t & 63;
    const int dg = t >> 6;
    const int e = (b - 2048) * 64 + l;
    float s = 0.f;
#pragma unroll 8
    for (int d = dg * 64; d < dg * 64 + 64; ++d) {
      const float v = emb[(size_t)d * NEMB + e];
      s = fmaf(v, v, s);
    }
    red[dg][l] = s;
    __syncthreads();
    if (dg == 0) enorm[e] = red[0][l] + red[1][l] + red[2][l] + red[3][l];
  }
}

// ---------------------------------------------------------------------------
// MFMA dist+argmin — R2-proven kernel, verbatim. Block 256 thr = 4 waves,
// tile 128 rows x 128 codes, wave tile 64x64 (4x4 of 16x16x32 mfma), BK=64,
// 3 mfma per (frag,kstep). Grid 512: bid>>2 = row-tile, bid&3 = code chunk.
// LDS: [row 128][16 chunks x 8 bf16]; chunk p of row n = k-octet ((p&7)^(n&7))
// of plane (p>>3). Staging = wave-uniform-base global_load_lds width 16.
__global__ __launch_bounds__(256, 2) void argmin_mfma_kernel(
    const unsigned short* __restrict__ z_hi, const unsigned short* __restrict__ z_lo,
    const unsigned short* __restrict__ e_hi, const unsigned short* __restrict__ e_lo,
    const float* __restrict__ enorm, unsigned long long* __restrict__ pack) {
  __shared__ short za[16384];  // 32 KB
  __shared__ short eb[16384];  // 32 KB
  const int tid = threadIdx.x;
  const int bid = blockIdx.x;
  const int r0 = (bid >> 2) * 128;
  const int ebase = (bid & 3) * 2048;
  const int tx = tid & 15;
  const int q = (tid >> 4) & 3;
  const int wave = tid >> 6;
  const int wm = wave & 1;   // row half
  const int wn = wave >> 1;  // col half

  float rmin[4][4];
  int ridx[4][4];
#pragma unroll
  for (int i = 0; i < 4; ++i)
#pragma unroll
    for (int r = 0; r < 4; ++r) { rmin[i][r] = 3.4028235e38f; ridx[i][r] = 0; }

  for (int nt = 0; nt < 16; ++nt) {
    const int n0 = ebase + nt * 128;
    f32x4 acc[4][4];
#pragma unroll
    for (int i = 0; i < 4; ++i)
#pragma unroll
      for (int j = 0; j < 4; ++j) acc[i][j] = (f32x4)0.0f;

    for (int kt = 0; kt < 4; ++kt) {
      const int k0 = kt * 64;
      __syncthreads();  // previous tile fully consumed
#pragma unroll
      for (int it = 0; it < 8; ++it) {
        const int P = tid + it * 256;  // chunk id 0..2047
        const int row = P >> 4;
        const int p = P & 15;
        const int o = (p & 7) ^ (row & 7);
        const unsigned short* zsrc =
            ((p & 8) ? z_lo : z_hi) + (size_t)(r0 + row) * DIMC + k0 + o * 8;
        __builtin_amdgcn_global_load_lds(
            (const __attribute__((address_space(1))) unsigned int*)zsrc,
            (__attribute__((address_space(3))) unsigned int*)&za[P * 8], 16, 0, 0);
        const unsigned short* esrc =
            ((p & 8) ? e_lo : e_hi) + (size_t)(n0 + row) * DIMC + k0 + o * 8;
        __builtin_amdgcn_global_load_lds(
            (const __attribute__((address_space(1))) unsigned int*)esrc,
            (__attribute__((address_space(3))) unsigned int*)&eb[P * 8], 16, 0, 0);
      }
      __syncthreads();  // drain + publish
#pragma unroll
      for (int ks = 0; ks < 2; ++ks) {
        short8 ah[4], al[4], bh[4], bl[4];
#pragma unroll
        for (int i = 0; i < 4; ++i) {
          const int rl = wm * 64 + i * 16 + tx;
          const int oa = (ks * 4 + q) ^ (rl & 7);
          ah[i] = *reinterpret_cast<const short8*>(&za[rl * 128 + oa * 8]);
          al[i] = *reinterpret_cast<const short8*>(&za[rl * 128 + (oa + 8) * 8]);
          const int cl = wn * 64 + i * 16 + tx;
          const int ob = (ks * 4 + q) ^ (cl & 7);
          bh[i] = *reinterpret_cast<const short8*>(&eb[cl * 128 + ob * 8]);
          bl[i] = *reinterpret_cast<const short8*>(&eb[cl * 128 + (ob + 8) * 8]);
        }
#pragma unroll
        for (int i = 0; i < 4; ++i)
#pragma unroll
          for (int j = 0; j < 4; ++j) {
            acc[i][j] = __builtin_amdgcn_mfma_f32_16x16x32_bf16(ah[i], bh[j],
                                                               acc[i][j], 0, 0, 0);
            acc[i][j] = __builtin_amdgcn_mfma_f32_16x16x32_bf16(ah[i], bl[j],
                                                               acc[i][j], 0, 0, 0);
            acc[i][j] = __builtin_amdgcn_mfma_f32_16x16x32_bf16(al[i], bh[j],
                                                               acc[i][j], 0, 0, 0);
          }
      }
    }
    // epilogue: score = ||e||^2 - 2*dot, running first-min argmin.
    // D frag: row = q*4 + r, col = tx (m89-verified 16x16 C/D layout)
#pragma unroll
    for (int j = 0; j < 4; ++j) {
      const int col = n0 + wn * 64 + j * 16 + tx;
      const float en = enorm[col];
#pragma unroll
      for (int i = 0; i < 4; ++i)
#pragma unroll
        for (int r = 0; r < 4; ++r) {
          const float s = en - 2.0f * acc[i][j][r];
          if (s < rmin[i][r]) { rmin[i][r] = s; ridx[i][r] = col; }
        }
    }
  }
  // reduce across the 16 tx lanes (same rows), then one atomicMin per row
#pragma unroll
  for (int i = 0; i < 4; ++i)
#pragma unroll
    for (int r = 0; r < 4; ++r) {
      float v = rmin[i][r];
      int ix = ridx[i][r];
#pragma unroll
      for (int off = 1; off < 16; off <<= 1) {
        const float ov = __shfl_xor(v, off, 16);
        const int oi = __shfl_xor(ix, off, 16);
        if (ov < v || (ov == v && oi < ix)) { v = ov; ix = oi; }
      }
      if (tx == 0) {
        const unsigned int fb = __float_as_uint(v);
        const unsigned int sb = (fb & 0x80000000u) ? ~fb : (fb | 0x80000000u);
        const unsigned long long key =
            ((unsigned long long)sb << 13) | (unsigned long long)(unsigned)ix;
        atomicMin(&pack[r0 + wm * 64 + i * 16 + q * 4 + r], key);
      }
    }
}

// ---------------------------------------------------------------------------
// Gather quantize (reconstruct fp32 = hi+lo from bf16 planes), extract index,
// diff partial, scatter embed_sum/count. 1 wave per row.
__global__ __launch_bounds__(256) void gather_update_kernel(
    const float* __restrict__ z, const unsigned short* __restrict__ e_hi,
    const unsigned short* __restrict__ e_lo,
    const unsigned long long* __restrict__ pack, float* __restrict__ out_q,
    float* __restrict__ out_idx, float* __restrict__ embsum,
    float* __restrict__ count, float* __restrict__ diff_acc) {
  const int row = blockIdx.x * 4 + (threadIdx.x >> 6);
  const int lane = threadIdx.x & 63;
  const int e = (int)(pack[row] & 8191ULL);
  if (lane == 0) out_idx[row] = (float)e;
  const float4 zv =
      *reinterpret_cast<const float4*>(&z[(size_t)row * DIMC + lane * 4]);
  const ushort4 h =
      *reinterpret_cast<const ushort4*>(&e_hi[(size_t)e * DIMC + lane * 4]);
  const ushort4 l =
      *reinterpret_cast<const ushort4*>(&e_lo[(size_t)e * DIMC + lane * 4]);
  const float q0 = bf16_f(h.x) + bf16_f(l.x);
  const float q1 = bf16_f(h.y) + bf16_f(l.y);
  const float q2 = bf16_f(h.z) + bf16_f(l.z);
  const float q3 = bf16_f(h.w) + bf16_f(l.w);
  const float d0 = q0 - zv.x, d1 = q1 - zv.y, d2 = q2 - zv.z, d3 = q3 - zv.w;
  float4 st;  // z + (q - z), replicating reference op order
  st.x = zv.x + d0; st.y = zv.y + d1; st.z = zv.z + d2; st.w = zv.w + d3;
  *reinterpret_cast<float4*>(&out_q[(size_t)row * DIMC + lane * 4]) = st;

  atomicAdd(&embsum[(size_t)e * DIMC + lane * 4 + 0], zv.x);
  atomicAdd(&embsum[(size_t)e * DIMC + lane * 4 + 1], zv.y);
  atomicAdd(&embsum[(size_t)e * DIMC + lane * 4 + 2], zv.z);
  atomicAdd(&embsum[(size_t)e * DIMC + lane * 4 + 3], zv.w);

  float local = d0 * d0 + d1 * d1 + d2 * d2 + d3 * d3;
#pragma unroll
  for (int off = 32; off > 0; off >>= 1) local += __shfl_down(local, off, 64);

  __shared__ float dred[4];
  if (lane == 0) {
    dred[threadIdx.x >> 6] = local;
    atomicAdd(&count[e], 1.0f);
  }
  __syncthreads();
  if (threadIdx.x == 0)
    atomicAdd(diff_acc, dred[0] + dred[1] + dred[2] + dred[3]);
}

// ---------------------------------------------------------------------------
// fin_a: blocks [0,512): avgtmp[d][e] = 0.99*eavg + 0.01*embsum[e][d] (tiled
// transpose). blocks [512,544): new_cluster_size + n partial + diff finalize.
__global__ __launch_bounds__(256) void fin_a_kernel(
    const float* __restrict__ eavg, const float* __restrict__ embsum,
    float* __restrict__ avgtmp, const float* __restrict__ cs,
    const float* __restrict__ count, float* __restrict__ out_ncs,
    float* __restrict__ out_diff, const float* __restrict__ diff_acc,
    float* __restrict__ n_acc) {
  const int b = blockIdx.x;
  const int t = threadIdx.x;
  __shared__ float tile[64][68];
  if (b < 512) {
    const int e0 = (b & 127) * 64;
    const int d0 = (b >> 7) * 64;
    const int c4 = (t & 15) * 4;
    const int rr = t >> 4;
#pragma unroll
    for (int i = 0; i < 4; ++i) {
      const int er = rr + i * 16;
      const float4 v = *reinterpret_cast<const float4*>(
          &embsum[(size_t)(e0 + er) * DIMC + d0 + c4]);
      *reinterpret_cast<float4*>(&tile[er][c4]) = v;
    }
    __syncthreads();
#pragma unroll
    for (int i = 0; i < 4; ++i) {
      const int dr = rr + i * 16;
      const size_t g = (size_t)(d0 + dr) * NEMB + e0 + c4;
      const float4 av = *reinterpret_cast<const float4*>(&eavg[g]);
      float4 o;
      o.x = av.x * 0.99f + 0.01f * tile[c4 + 0][dr];
      o.y = av.y * 0.99f + 0.01f * tile[c4 + 1][dr];
      o.z = av.z * 0.99f + 0.01f * tile[c4 + 2][dr];
      o.w = av.w * 0.99f + 0.01f * tile[c4 + 3][dr];
      *reinterpret_cast<float4*>(&avgtmp[g]) = o;
    }
  } else {
    const int g = (b - 512) * 256 + t;
    const float ncs = cs[g] * 0.99f + 0.01f * count[g];
    out_ncs[g] = ncs;
    float s = ncs;
#pragma unroll
    for (int off = 32; off > 0; off >>= 1) s += __shfl_down(s, off, 64);
    __shared__ float red[4];
    if ((t & 63) == 0) red[t >> 6] = s;
    __syncthreads();
    if (t == 0) atomicAdd(n_acc, red[0] + red[1] + red[2] + red[3]);
    if (g == 0) out_diff[0] = diff_acc[0] * (1.0f / 4194304.0f);
  }
}

// ---------------------------------------------------------------------------
// fin2: out_avg[g] = avgtmp[g] (overwrites embsum scratch, consumed);
// new_embedding[g] = avgtmp[g]/smoothed(e) in place.
__global__ __launch_bounds__(256) void fin2_kernel(
    const float* __restrict__ ncs_out, const float* __restrict__ n_acc,
    float* __restrict__ out_avg, float* __restrict__ out_emb_and_avgtmp) {
  const int g = blockIdx.x * 256 + threadIdx.x;
  const int e = g & 8191;
  const float avg = out_emb_and_avgtmp[g];
  const float n = n_acc[0];
  const float ncs = ncs_out[e];
  const float smoothed = (ncs + 1e-5f) / (n + (float)NEMB * 1e-5f) * n;
  out_avg[g] = avg;
  out_emb_and_avgtmp[g] = avg / smoothed;
}

// ---------------------------------------------------------------------------
extern "C" void kernel_launch(void* const* d_in, const int* in_sizes, int n_in,
                              void* d_out, int out_size, void* d_ws,
                              size_t ws_size, hipStream_t stream) {
  const float* z = (const float*)d_in[0];
  const float* emb = (const float*)d_in[1];
  const float* cs = (const float*)d_in[2];
  const float* eavg = (const float*)d_in[3];
  float* out = (float*)d_out;
  float* ws = (float*)d_ws;

  unsigned short* e_hi = (unsigned short*)(ws + WS_EHI);
  unsigned short* e_lo = (unsigned short*)(ws + WS_ELO);
  float* ws_count = ws + WS_COUNT;
  float* ws_diff = ws + WS_DIFF;
  float* ws_n = ws + WS_N;
  float* ws_enorm = ws + WS_ENORM;
  unsigned long long* ws_pack = (unsigned long long*)(ws + WS_PACK);

  // d_out-aliased scratch (rewritten before readback):
  unsigned short* z_hi = (unsigned short*)(out + OUT_Q);
  unsigned short* z_lo = (unsigned short*)(out + OUT_Q + 2097152);
  float* embsum = out + OUT_NEWAVG;  // [e][d]
  float* avgtmp = out + OUT_NEWEMB;  // [d][e], becomes new_embedding in fin2

  hipMemsetAsync(ws_count, 0, (size_t)8194 * sizeof(float), stream);
  hipMemsetAsync(ws_pack, 0xFF, (size_t)NROWS * sizeof(unsigned long long),
                 stream);

  prep_kernel<<<2176, 256, 0, stream>>>(z, emb, z_hi, z_lo, e_hi, e_lo,
                                        ws_enorm, embsum);
  argmin_mfma_kernel<<<512, 256, 0, stream>>>(z_hi, z_lo, e_hi, e_lo, ws_enorm,
                                              ws_pack);
  gather_update_kernel<<<NROWS / 4, 256, 0, stream>>>(
      z, e_hi, e_lo, ws_pack, out + OUT_Q, out + OUT_IDX, embsum, ws_count,
      ws_diff);
  fin_a_kernel<<<544, 256, 0, stream>>>(eavg, embsum, avgtmp, cs, ws_count,
                                        out + OUT_NEWCS, out + OUT_DIFF,
                                        ws_diff, ws_n);
  fin2_kernel<<<(DIMC * NEMB) / 256, 256, 0, stream>>>(
      out + OUT_NEWCS, ws_n, out + OUT_NEWAVG, avgtmp);
}

// Round 5
// 390.020 us; speedup vs baseline: 3.7364x; 1.0152x over previous
//
#include <hip/hip_runtime.h>

// ---------------------------------------------------------------------------
// VectorQuantizer: z(16,32,32,256) fp32, embedding(256,8192), cluster_size(8192),
// embedding_avg(256,8192).
// Outputs (concat, fp32): quantize_st[4194304], diff[1], embed_ind[16384](as float),
// new_embedding[2097152], new_cluster_size[8192], new_embedding_avg[2097152]
//
// R5: minimal graph — 5 kernels, 0 memsets. argmin is R4-verbatim (proven).
//   - all init (embsum zero, pack 0xFF, count/diff zero) fused into prep
//   - n computed in prep closed-form: n = 0.99*sum(cs) + 0.01*16384
//   - fin1 writes new_embedding directly (transpose+EMA+divide one pass)
//   - fin2b derives new_embedding_avg = new_embedding * smoothed (elementwise,
//     kills the second transposed pass and the embsum aliasing race)
// Aliasing timeline:
//   OUT_Q:      z_hi/z_lo planes (prep) -> quantize_st (gather)
//   OUT_NEWAVG: embsum [e][d] zeroed (prep), scattered (gather), read (fin1),
//               -> new_embedding_avg (fin2b)
//   OUT_NEWEMB: new_embedding (fin1), read by fin2b
// ---------------------------------------------------------------------------

#define DIMC  256
#define NEMB  8192
#define NROWS 16384

// d_out offsets (float elements)
#define OUT_Q      0u
#define OUT_DIFF   4194304u
#define OUT_IDX    4194305u
#define OUT_NEWEMB 4210689u
#define OUT_NEWCS  6307841u
#define OUT_NEWAVG 6316033u

// d_ws offsets (float elements) — total 2146308 floats = 8.59 MB
#define WS_EHI    0u          // bf16[8192][256] transposed emb hi
#define WS_ELO    1048576u    // bf16[8192][256] transposed emb lo
#define WS_COUNT  2097152u    // [NEMB]
#define WS_DIFF   2105344u    // [1]
#define WS_N      2105345u    // [1]  (written by prep, closed-form)
#define WS_ENORM  2105346u    // [NEMB] exact ||e||^2
#define WS_PACK   2113540u    // u64[NROWS]; byte 8454160 % 16 == 0 (16-aligned)

typedef __attribute__((ext_vector_type(8))) short short8;
typedef __attribute__((ext_vector_type(4))) float f32x4;

// round-to-nearest-even fp32 -> bf16 split: x ~= hi + lo
__device__ inline void split_bf16(float x, unsigned short& h, unsigned short& l) {
  unsigned u = __float_as_uint(x);
  unsigned r = u + 0x7FFFu + ((u >> 16) & 1u);
  h = (unsigned short)(r >> 16);
  float hf = __uint_as_float((unsigned)h << 16);
  float lo = x - hf;
  unsigned u2 = __float_as_uint(lo);
  unsigned r2 = u2 + 0x7FFFu + ((u2 >> 16) & 1u);
  l = (unsigned short)(r2 >> 16);
}

__device__ inline float bf16_f(unsigned short u) {
  return __uint_as_float((unsigned)u << 16);
}

// ---------------------------------------------------------------------------
// Fused prep: [0,1024) z split | [1024,1536) emb transpose/split |
// [1536,2048) embsum zero | [2048,2176) exact enorm | [2176,2184) pack 0xFF |
// [2184] count+diff zero | [2185] sum(cs) -> n closed-form
__global__ __launch_bounds__(256) void prep_kernel(
    const float* __restrict__ z, const float* __restrict__ emb,
    const float* __restrict__ cs, unsigned short* __restrict__ z_hi,
    unsigned short* __restrict__ z_lo, unsigned short* __restrict__ e_hi,
    unsigned short* __restrict__ e_lo, float* __restrict__ enorm,
    float* __restrict__ embsum, unsigned long long* __restrict__ pack,
    float* __restrict__ count_diff, float* __restrict__ n_out) {
  const int b = blockIdx.x;
  const int t = threadIdx.x;
  __shared__ float tile[64][68];
  __shared__ float red[4][64];

  if (b < 1024) {
#pragma unroll
    for (int it = 0; it < 4; ++it) {
      const int idx = (b * 256 + t) + it * 262144;
      const float4 v = reinterpret_cast<const float4*>(z)[idx];
      ushort4 h, l;
      split_bf16(v.x, h.x, l.x);
      split_bf16(v.y, h.y, l.y);
      split_bf16(v.z, h.z, l.z);
      split_bf16(v.w, h.w, l.w);
      reinterpret_cast<ushort4*>(z_hi)[idx] = h;
      reinterpret_cast<ushort4*>(z_lo)[idx] = l;
    }
  } else if (b < 1536) {
    const int bb = b - 1024;
    const int n0 = (bb & 127) * 64;
    const int k0 = (bb >> 7) * 64;
    const int c4 = (t & 15) * 4;
    const int rr = t >> 4;
#pragma unroll
    for (int i = 0; i < 4; ++i) {
      const int kl = rr + i * 16;
      const float4 v = *reinterpret_cast<const float4*>(
          &emb[(size_t)(k0 + kl) * NEMB + n0 + c4]);
      *reinterpret_cast<float4*>(&tile[kl][c4]) = v;
    }
    __syncthreads();
#pragma unroll
    for (int i = 0; i < 4; ++i) {
      const int nr = rr + i * 16;
      float4 v;
      v.x = tile[c4 + 0][nr];
      v.y = tile[c4 + 1][nr];
      v.z = tile[c4 + 2][nr];
      v.w = tile[c4 + 3][nr];
      const size_t off = (size_t)(n0 + nr) * DIMC + k0 + c4;
      ushort4 h, l;
      split_bf16(v.x, h.x, l.x);
      split_bf16(v.y, h.y, l.y);
      split_bf16(v.z, h.z, l.z);
      split_bf16(v.w, h.w, l.w);
      *reinterpret_cast<ushort4*>(&e_hi[off]) = h;
      *reinterpret_cast<ushort4*>(&e_lo[off]) = l;
    }
  } else if (b < 2048) {
    const int bb = b - 1536;
    const float4 zero = {0.f, 0.f, 0.f, 0.f};
#pragma unroll
    for (int it = 0; it < 4; ++it)
      reinterpret_cast<float4*>(embsum)[bb * 1024 + t + it * 256] = zero;
  } else if (b < 2176) {
    // exact enorm, R2 summation order
    const int l = t & 63;
    const int dg = t >> 6;
    const int e = (b - 2048) * 64 + l;
    float s = 0.f;
#pragma unroll 8
    for (int d = dg * 64; d < dg * 64 + 64; ++d) {
      const float v = emb[(size_t)d * NEMB + e];
      s = fmaf(v, v, s);
    }
    red[dg][l] = s;
    __syncthreads();
    if (dg == 0) enorm[e] = red[0][l] + red[1][l] + red[2][l] + red[3][l];
  } else if (b < 2184) {
    const int bb = b - 2176;
    const uint4 ff = {~0u, ~0u, ~0u, ~0u};  // ws_pack is 16-aligned
#pragma unroll
    for (int it = 0; it < 4; ++it)
      reinterpret_cast<uint4*>(pack)[bb * 1024 + t + it * 256] = ff;
  } else if (b == 2184) {
    for (int i = t; i < 8193; i += 256) count_diff[i] = 0.f;  // count + diff
  } else {
    // n = 0.99*sum(cs) + 0.01*16384 (sum(count) == NROWS exactly)
    float s = 0.f;
#pragma unroll
    for (int i = 0; i < 32; ++i) s += cs[t + i * 256];
#pragma unroll
    for (int off = 32; off > 0; off >>= 1) s += __shfl_down(s, off, 64);
    if ((t & 63) == 0) red[0][t >> 6] = s;
    __syncthreads();
    if (t == 0)
      n_out[0] = 0.99f * (red[0][0] + red[0][1] + red[0][2] + red[0][3]) +
                 163.84f;
  }
}

// ---------------------------------------------------------------------------
// MFMA dist+argmin — R4 kernel, VERBATIM (proven). Block 256 thr = 4 waves,
// tile 128 rows x 128 codes, wave tile 64x64 (4x4 of 16x16x32 mfma), BK=64,
// 3 mfma per (frag,kstep). Grid 512: bid>>2 = row-tile, bid&3 = code chunk.
__global__ __launch_bounds__(256, 2) void argmin_mfma_kernel(
    const unsigned short* __restrict__ z_hi, const unsigned short* __restrict__ z_lo,
    const unsigned short* __restrict__ e_hi, const unsigned short* __restrict__ e_lo,
    const float* __restrict__ enorm, unsigned long long* __restrict__ pack) {
  __shared__ short za[16384];  // 32 KB
  __shared__ short eb[16384];  // 32 KB
  const int tid = threadIdx.x;
  const int bid = blockIdx.x;
  const int r0 = (bid >> 2) * 128;
  const int ebase = (bid & 3) * 2048;
  const int tx = tid & 15;
  const int q = (tid >> 4) & 3;
  const int wave = tid >> 6;
  const int wm = wave & 1;   // row half
  const int wn = wave >> 1;  // col half

  float rmin[4][4];
  int ridx[4][4];
#pragma unroll
  for (int i = 0; i < 4; ++i)
#pragma unroll
    for (int r = 0; r < 4; ++r) { rmin[i][r] = 3.4028235e38f; ridx[i][r] = 0; }

  for (int nt = 0; nt < 16; ++nt) {
    const int n0 = ebase + nt * 128;
    f32x4 acc[4][4];
#pragma unroll
    for (int i = 0; i < 4; ++i)
#pragma unroll
      for (int j = 0; j < 4; ++j) acc[i][j] = (f32x4)0.0f;

    for (int kt = 0; kt < 4; ++kt) {
      const int k0 = kt * 64;
      __syncthreads();  // previous tile fully consumed
#pragma unroll
      for (int it = 0; it < 8; ++it) {
        const int P = tid + it * 256;  // chunk id 0..2047
        const int row = P >> 4;
        const int p = P & 15;
        const int o = (p & 7) ^ (row & 7);
        const unsigned short* zsrc =
            ((p & 8) ? z_lo : z_hi) + (size_t)(r0 + row) * DIMC + k0 + o * 8;
        __builtin_amdgcn_global_load_lds(
            (const __attribute__((address_space(1))) unsigned int*)zsrc,
            (__attribute__((address_space(3))) unsigned int*)&za[P * 8], 16, 0, 0);
        const unsigned short* esrc =
            ((p & 8) ? e_lo : e_hi) + (size_t)(n0 + row) * DIMC + k0 + o * 8;
        __builtin_amdgcn_global_load_lds(
            (const __attribute__((address_space(1))) unsigned int*)esrc,
            (__attribute__((address_space(3))) unsigned int*)&eb[P * 8], 16, 0, 0);
      }
      __syncthreads();  // drain + publish
#pragma unroll
      for (int ks = 0; ks < 2; ++ks) {
        short8 ah[4], al[4], bh[4], bl[4];
#pragma unroll
        for (int i = 0; i < 4; ++i) {
          const int rl = wm * 64 + i * 16 + tx;
          const int oa = (ks * 4 + q) ^ (rl & 7);
          ah[i] = *reinterpret_cast<const short8*>(&za[rl * 128 + oa * 8]);
          al[i] = *reinterpret_cast<const short8*>(&za[rl * 128 + (oa + 8) * 8]);
          const int cl = wn * 64 + i * 16 + tx;
          const int ob = (ks * 4 + q) ^ (cl & 7);
          bh[i] = *reinterpret_cast<const short8*>(&eb[cl * 128 + ob * 8]);
          bl[i] = *reinterpret_cast<const short8*>(&eb[cl * 128 + (ob + 8) * 8]);
        }
#pragma unroll
        for (int i = 0; i < 4; ++i)
#pragma unroll
          for (int j = 0; j < 4; ++j) {
            acc[i][j] = __builtin_amdgcn_mfma_f32_16x16x32_bf16(ah[i], bh[j],
                                                               acc[i][j], 0, 0, 0);
            acc[i][j] = __builtin_amdgcn_mfma_f32_16x16x32_bf16(ah[i], bl[j],
                                                               acc[i][j], 0, 0, 0);
            acc[i][j] = __builtin_amdgcn_mfma_f32_16x16x32_bf16(al[i], bh[j],
                                                               acc[i][j], 0, 0, 0);
          }
      }
    }
    // epilogue: score = ||e||^2 - 2*dot, running first-min argmin.
#pragma unroll
    for (int j = 0; j < 4; ++j) {
      const int col = n0 + wn * 64 + j * 16 + tx;
      const float en = enorm[col];
#pragma unroll
      for (int i = 0; i < 4; ++i)
#pragma unroll
        for (int r = 0; r < 4; ++r) {
          const float s = en - 2.0f * acc[i][j][r];
          if (s < rmin[i][r]) { rmin[i][r] = s; ridx[i][r] = col; }
        }
    }
  }
#pragma unroll
  for (int i = 0; i < 4; ++i)
#pragma unroll
    for (int r = 0; r < 4; ++r) {
      float v = rmin[i][r];
      int ix = ridx[i][r];
#pragma unroll
      for (int off = 1; off < 16; off <<= 1) {
        const float ov = __shfl_xor(v, off, 16);
        const int oi = __shfl_xor(ix, off, 16);
        if (ov < v || (ov == v && oi < ix)) { v = ov; ix = oi; }
      }
      if (tx == 0) {
        const unsigned int fb = __float_as_uint(v);
        const unsigned int sb = (fb & 0x80000000u) ? ~fb : (fb | 0x80000000u);
        const unsigned long long key =
            ((unsigned long long)sb << 13) | (unsigned long long)(unsigned)ix;
        atomicMin(&pack[r0 + wm * 64 + i * 16 + q * 4 + r], key);
      }
    }
}

// ---------------------------------------------------------------------------
// Gather quantize (reconstruct fp32 = hi+lo), extract index, diff partial,
// scatter embed_sum/count. 1 wave per row. (R4 verbatim)
__global__ __launch_bounds__(256) void gather_update_kernel(
    const float* __restrict__ z, const unsigned short* __restrict__ e_hi,
    const unsigned short* __restrict__ e_lo,
    const unsigned long long* __restrict__ pack, float* __restrict__ out_q,
    float* __restrict__ out_idx, float* __restrict__ embsum,
    float* __restrict__ count, float* __restrict__ diff_acc) {
  const int row = blockIdx.x * 4 + (threadIdx.x >> 6);
  const int lane = threadIdx.x & 63;
  const int e = (int)(pack[row] & 8191ULL);
  if (lane == 0) out_idx[row] = (float)e;
  const float4 zv =
      *reinterpret_cast<const float4*>(&z[(size_t)row * DIMC + lane * 4]);
  const ushort4 h =
      *reinterpret_cast<const ushort4*>(&e_hi[(size_t)e * DIMC + lane * 4]);
  const ushort4 l =
      *reinterpret_cast<const ushort4*>(&e_lo[(size_t)e * DIMC + lane * 4]);
  const float q0 = bf16_f(h.x) + bf16_f(l.x);
  const float q1 = bf16_f(h.y) + bf16_f(l.y);
  const float q2 = bf16_f(h.z) + bf16_f(l.z);
  const float q3 = bf16_f(h.w) + bf16_f(l.w);
  const float d0 = q0 - zv.x, d1 = q1 - zv.y, d2 = q2 - zv.z, d3 = q3 - zv.w;
  float4 st;
  st.x = zv.x + d0; st.y = zv.y + d1; st.z = zv.z + d2; st.w = zv.w + d3;
  *reinterpret_cast<float4*>(&out_q[(size_t)row * DIMC + lane * 4]) = st;

  atomicAdd(&embsum[(size_t)e * DIMC + lane * 4 + 0], zv.x);
  atomicAdd(&embsum[(size_t)e * DIMC + lane * 4 + 1], zv.y);
  atomicAdd(&embsum[(size_t)e * DIMC + lane * 4 + 2], zv.z);
  atomicAdd(&embsum[(size_t)e * DIMC + lane * 4 + 3], zv.w);

  float local = d0 * d0 + d1 * d1 + d2 * d2 + d3 * d3;
#pragma unroll
  for (int off = 32; off > 0; off >>= 1) local += __shfl_down(local, off, 64);

  __shared__ float dred[4];
  if (lane == 0) {
    dred[threadIdx.x >> 6] = local;
    atomicAdd(&count[e], 1.0f);
  }
  __syncthreads();
  if (threadIdx.x == 0)
    atomicAdd(diff_acc, dred[0] + dred[1] + dred[2] + dred[3]);
}

// ---------------------------------------------------------------------------
// fin1: blocks [0,512): new_embedding[d][e] = (0.99*eavg + 0.01*embsum[e][d])
// * (1/smoothed(e)) — transpose + EMA + divide, one pass. smoothed recomputed
// locally from cs/count + closed-form n (no cross-kernel reduction).
// blocks [512,544): new_cluster_size + diff finalize.
__global__ __launch_bounds__(256) void fin1_kernel(
    const float* __restrict__ eavg, const float* __restrict__ embsum,
    const float* __restrict__ cs, const float* __restrict__ count,
    const float* __restrict__ n_ptr, const float* __restrict__ diff_acc,
    float* __restrict__ out_emb, float* __restrict__ out_ncs,
    float* __restrict__ out_diff) {
  const int b = blockIdx.x;
  const int t = threadIdx.x;
  __shared__ float tile[64][68];
  __shared__ float rs[64];
  if (b < 512) {
    const int e0 = (b & 127) * 64;
    const int d0 = (b >> 7) * 64;
    const int c4 = (t & 15) * 4;
    const int rr = t >> 4;
    if (t < 64) {
      const float n = n_ptr[0];
      const float ncs = cs[e0 + t] * 0.99f + 0.01f * count[e0 + t];
      const float sm = (ncs + 1e-5f) / (n + 0.08192f) * n;
      rs[t] = 1.0f / sm;
    }
#pragma unroll
    for (int i = 0; i < 4; ++i) {
      const int er = rr + i * 16;
      const float4 v = *reinterpret_cast<const float4*>(
          &embsum[(size_t)(e0 + er) * DIMC + d0 + c4]);
      *reinterpret_cast<float4*>(&tile[er][c4]) = v;
    }
    __syncthreads();
#pragma unroll
    for (int i = 0; i < 4; ++i) {
      const int dr = rr + i * 16;
      const size_t g = (size_t)(d0 + dr) * NEMB + e0 + c4;
      const float4 av = *reinterpret_cast<const float4*>(&eavg[g]);
      float4 o;
      o.x = (av.x * 0.99f + 0.01f * tile[c4 + 0][dr]) * rs[c4 + 0];
      o.y = (av.y * 0.99f + 0.01f * tile[c4 + 1][dr]) * rs[c4 + 1];
      o.z = (av.z * 0.99f + 0.01f * tile[c4 + 2][dr]) * rs[c4 + 2];
      o.w = (av.w * 0.99f + 0.01f * tile[c4 + 3][dr]) * rs[c4 + 3];
      *reinterpret_cast<float4*>(&out_emb[g]) = o;
    }
  } else {
    const int g = (b - 512) * 256 + t;
    out_ncs[g] = cs[g] * 0.99f + 0.01f * count[g];
    if (g == 0) out_diff[0] = diff_acc[0] * (1.0f / 4194304.0f);
  }
}

// ---------------------------------------------------------------------------
// fin2b: new_embedding_avg[g] = new_embedding[g] * smoothed(e). Elementwise —
// overwrites embsum scratch (fully consumed by fin1). ~2 ulp vs direct.
__global__ __launch_bounds__(256) void fin2b_kernel(
    const float* __restrict__ cs, const float* __restrict__ count,
    const float* __restrict__ n_ptr, const float* __restrict__ out_emb,
    float* __restrict__ out_avg) {
  const int g = blockIdx.x * 256 + threadIdx.x;
  const int e = g & 8191;
  const float n = n_ptr[0];
  const float ncs = cs[e] * 0.99f + 0.01f * count[e];
  const float sm = (ncs + 1e-5f) / (n + 0.08192f) * n;
  out_avg[g] = out_emb[g] * sm;
}

// ---------------------------------------------------------------------------
extern "C" void kernel_launch(void* const* d_in, const int* in_sizes, int n_in,
                              void* d_out, int out_size, void* d_ws,
                              size_t ws_size, hipStream_t stream) {
  const float* z = (const float*)d_in[0];
  const float* emb = (const float*)d_in[1];
  const float* cs = (const float*)d_in[2];
  const float* eavg = (const float*)d_in[3];
  float* out = (float*)d_out;
  float* ws = (float*)d_ws;

  unsigned short* e_hi = (unsigned short*)(ws + WS_EHI);
  unsigned short* e_lo = (unsigned short*)(ws + WS_ELO);
  float* ws_count = ws + WS_COUNT;
  float* ws_diff = ws + WS_DIFF;
  float* ws_n = ws + WS_N;
  float* ws_enorm = ws + WS_ENORM;
  unsigned long long* ws_pack = (unsigned long long*)(ws + WS_PACK);

  // d_out-aliased scratch (rewritten before readback):
  unsigned short* z_hi = (unsigned short*)(out + OUT_Q);
  unsigned short* z_lo = (unsigned short*)(out + OUT_Q + 2097152);
  float* embsum = out + OUT_NEWAVG;  // [e][d]

  prep_kernel<<<2186, 256, 0, stream>>>(z, emb, cs, z_hi, z_lo, e_hi, e_lo,
                                        ws_enorm, embsum, ws_pack, ws_count,
                                        ws_n);
  argmin_mfma_kernel<<<512, 256, 0, stream>>>(z_hi, z_lo, e_hi, e_lo, ws_enorm,
                                              ws_pack);
  gather_update_kernel<<<NROWS / 4, 256, 0, stream>>>(
      z, e_hi, e_lo, ws_pack, out + OUT_Q, out + OUT_IDX, embsum, ws_count,
      ws_diff);
  fin1_kernel<<<544, 256, 0, stream>>>(eavg, embsum, cs, ws_count, ws_n,
                                       ws_diff, out + OUT_NEWEMB,
                                       out + OUT_NEWCS, out + OUT_DIFF);
  fin2b_kernel<<<(DIMC * NEMB) / 256, 256, 0, stream>>>(
      cs, ws_count, ws_n, out + OUT_NEWEMB, out + OUT_NEWAVG);
}